// Round 6
// baseline (696.844 us; speedup 1.0000x reference)
//
#include <hip/hip_runtime.h>

// ---------- types ----------
typedef short  short8 __attribute__((ext_vector_type(8)));
typedef short  sv4    __attribute__((ext_vector_type(4)));   // NB: 'short4' collides with HIP's own typedef
typedef __bf16 bf16x8 __attribute__((ext_vector_type(8)));
typedef float  f32x4  __attribute__((ext_vector_type(4)));

__device__ __forceinline__ float bf2f(short s) {
    unsigned u = ((unsigned)(unsigned short)s) << 16;
    return __builtin_bit_cast(float, u);
}
__device__ __forceinline__ short f2bf(float f) {
    unsigned u = __builtin_bit_cast(unsigned, f);
    u += 0x7fffu + ((u >> 16) & 1u);   // RNE
    return (short)(u >> 16);
}
__device__ __forceinline__ f32x4 mfma16(short8 a, short8 b, f32x4 c) {
    return __builtin_amdgcn_mfma_f32_16x16x32_bf16(
        __builtin_bit_cast(bf16x8, a), __builtin_bit_cast(bf16x8, b), c, 0, 0, 0);
}

// Geometry: B=8, H=W=64, C=256, CQ=64
// x NHWC: idx = ((b*64+h)*64+w)*256 + c
// planar:  [b][c][h][w]  idx = ((b*256+c)*64+h)*64+w

// ---------- 0. dtype detect ----------
__global__ __launch_bounds__(256) void detect_k(const short* x, int* flag)
{
    __shared__ int red[256];
    int t = threadIdx.x;
    int cnt = 0;
    for (int i = t; i < 4096; i += 256) {
        int e = (x[2 * i] >> 7) & 0xFF;
        cnt += (e >= 100 && e <= 140) ? 1 : 0;
    }
    red[t] = cnt; __syncthreads();
    for (int s = 128; s > 0; s >>= 1) { if (t < s) red[t] += red[t + s]; __syncthreads(); }
    if (t == 0) *flag = (red[0] < 3277) ? 1 : 0;   // 1 => inputs are fp32
}

// ---------- 1a. x -> bf16 ----------
__global__ __launch_bounds__(256) void convert_x(const void* x, short* xb, const int* flagp)
{
    int f32 = *flagp;
    size_t i = ((size_t)blockIdx.x * 256 + threadIdx.x) * 8;
    short8 v;
    if (f32) {
        const float* fs = (const float*)x + i;
        f32x4 a = *(const f32x4*)fs;
        f32x4 b = *(const f32x4*)(fs + 4);
#pragma unroll
        for (int l = 0; l < 4; l++) { v[l] = f2bf(a[l]); v[4 + l] = f2bf(b[l]); }
    } else {
        v = *(const short8*)((const short*)x + i);
    }
    *(short8*)(xb + i) = v;
}

// ---------- 1b. weight repack + bias concat ----------
struct Ptrs {
    const void *wq, *wq1, *wq2, *wq3, *wq4, *wk, *wv;
    const void *bq, *bq1, *bq2, *bq3, *bq4, *bk, *bv, *gm;
};

__global__ __launch_bounds__(256) void convert_k(Ptrs P, short* wp, short* bb, const int* flagp)
{
    int f32 = *flagp;
    int idx = blockIdx.x * 256 + threadIdx.x;
    if (idx < 1179648) {
        const void* src; int Cout, base;
        if      (idx <   16384) { src = P.wq;  Cout =  64; base = 0; }
        else if (idx <  163840) { src = P.wq1; Cout =  64; base = 16384; }
        else if (idx <  311296) { src = P.wq2; Cout =  64; base = 163840; }
        else if (idx <  458752) { src = P.wq3; Cout =  64; base = 311296; }
        else if (idx <  524288) { src = P.wq4; Cout = 256; base = 458752; }
        else if (idx < 1114112) { src = P.wk;  Cout = 256; base = 524288; }
        else                    { src = P.wv;  Cout = 256; base = 1114112; }
        int rem = idx - base;
        int t   = rem / (Cout * 256);
        int r2  = rem - t * Cout * 256;
        int co  = r2 >> 8;
        int ci  = r2 & 255;
        int si  = (t * 256 + ci) * Cout + co;
        wp[idx] = f32 ? f2bf(((const float*)src)[si]) : ((const short*)src)[si];
    } else if (idx < 1179648 + 1025) {
        int j = idx - 1179648;
        const void* src; int off;
        if      (j <   64) { src = P.bq;  off = j; }
        else if (j <  128) { src = P.bq1; off = j - 64; }
        else if (j <  192) { src = P.bq2; off = j - 128; }
        else if (j <  256) { src = P.bq3; off = j - 192; }
        else if (j <  512) { src = P.bq4; off = j - 256; }
        else if (j <  768) { src = P.bk;  off = j - 512; }
        else if (j < 1024) { src = P.bv;  off = j - 768; }
        else               { src = P.gm;  off = 0; }
        bb[j] = f32 ? f2bf(((const float*)src)[off]) : ((const short*)src)[off];
    }
}

// ---------- 2. fused conv: register-double-buffered implicit GEMM ----------
struct ConvJob {
    const short* src;   // NHWC bf16, Cin=256
    short*       dst;
    const short* wp;    // packed [t][co][ci]
    const short* bias;
    int Cout;           // 64 or 256
    int dil;
    int ntaps;          // 1 or 9
    int coff;           // dst channel offset (planar==0)
    int planar;         // 0: NHWC  1: [b][c][h][w]  2: [b][c][w][h]
};
struct ConvTable { ConvJob j[6]; int end[6]; };

// launch_bounds(256,3): ~170 VGPR budget so the 2-slice pipeline stays in regs.
__global__ __launch_bounds__(256, 3) void conv_all(ConvTable T)
{
    int wid  = threadIdx.x >> 6;
    int lane = threadIdx.x & 63;
    int gw   = blockIdx.x * 4 + wid;
    int ji = 0;
    while (ji < 5 && gw >= T.end[ji]) ji++;
    if (gw >= T.end[ji]) return;
    ConvJob J = T.j[ji];
    int g = gw - (ji ? T.end[ji - 1] : 0);

    int ntn = J.Cout >> 6;
    int nt  = g & (ntn - 1);
    int pt  = (ntn == 4) ? (g >> 2) : g;
    int b   = pt >> 6, h = pt & 63;

    int lrow = lane & 15;
    int q8   = (lane >> 4) << 3;

    f32x4 acc[4][4] = {};
    int nco[4];
#pragma unroll
    for (int ni = 0; ni < 4; ni++) nco[ni] = nt * 64 + ni * 16 + lrow;

    const short8 z8 = {};
    int S = J.ntaps * 8;                 // slices: (tap, kc)

    short8 Abuf[2][4], Bbuf[2][4];

    auto loadS = [&](int s, int bi) {
        int t = s >> 3, kc = s & 7;
        int dy = 0, dx = 0;
        if (J.ntaps == 9) { dy = (t / 3 - 1) * J.dil; dx = (t % 3 - 1) * J.dil; }
        int hh = h + dy;
        bool rv = ((unsigned)hh) < 64u;
#pragma unroll
        for (int mi = 0; mi < 4; mi++) {
            int ww = mi * 16 + lrow + dx;
            bool am = rv && (((unsigned)ww) < 64u);
            int aoff = am ? (((b * 64 + hh) * 64 + ww) * 256 + q8 + kc * 32) : 0;
            short8 v = *(const short8*)(J.src + aoff);
            Abuf[bi][mi] = am ? v : z8;
        }
        const short* wb = J.wp + (size_t)t * J.Cout * 256 + q8 + kc * 32;
#pragma unroll
        for (int ni = 0; ni < 4; ni++)
            Bbuf[bi][ni] = *(const short8*)(wb + (size_t)nco[ni] * 256);
    };
    auto domfma = [&](int bi) {
#pragma unroll
        for (int mi = 0; mi < 4; mi++)
#pragma unroll
            for (int ni = 0; ni < 4; ni++)
                acc[mi][ni] = mfma16(Abuf[bi][mi], Bbuf[bi][ni], acc[mi][ni]);
    };

    loadS(0, 0);
    for (int s = 0; s < S; s += 2) {
        if (s + 1 < S) loadS(s + 1, 1);
        domfma(0);
        if (s + 2 < S) loadS(s + 2, 0);
        if (s + 1 < S) domfma(1);
    }

    int rq = (lane >> 4) * 4;
    if (J.planar == 0) {
#pragma unroll
        for (int ni = 0; ni < 4; ni++) {
            int co = nco[ni];
            float bv = bf2f(J.bias[co]);
#pragma unroll
            for (int mi = 0; mi < 4; mi++) {
                int posbase = pt * 64 + mi * 16 + rq;
#pragma unroll
                for (int r = 0; r < 4; r++)
                    J.dst[(size_t)(posbase + r) * 256 + J.coff + co] = f2bf(acc[mi][ni][r] + bv);
            }
        }
    } else if (J.planar == 1) {          // dst[((b*256+co)*64+h)*64 + w]
#pragma unroll
        for (int ni = 0; ni < 4; ni++) {
            int co = nco[ni];
            float bv = bf2f(J.bias[co]);
            short* row = J.dst + ((size_t)(b * 256 + co) * 64 + h) * 64;
#pragma unroll
            for (int mi = 0; mi < 4; mi++) {
                sv4 o;
#pragma unroll
                for (int r = 0; r < 4; r++) o[r] = f2bf(acc[mi][ni][r] + bv);
                *(sv4*)(row + mi * 16 + rq) = o;
            }
        }
    } else {                             // dst[((b*256+co)*64+w)*64 + h]
#pragma unroll
        for (int ni = 0; ni < 4; ni++) {
            int co = nco[ni];
            float bv = bf2f(J.bias[co]);
            short* pl = J.dst + (size_t)(b * 256 + co) * 4096 + h;
#pragma unroll
            for (int mi = 0; mi < 4; mi++)
#pragma unroll
                for (int r = 0; r < 4; r++)
                    pl[(size_t)(mi * 16 + rq + r) * 64] = f2bf(acc[mi][ni][r] + bv);
        }
    }
}

// ---------- 3. energy: Et[b,c,w,i] = sum_j kp[b,c,i,j] * qp[b,c,w,j] ----------
// qp = q planar-transposed [b][c][w][j(=h)]; kp = k planar [b][c][i(=h)][j(=w)]
__global__ __launch_bounds__(256) void energy_mfma(const short* qp, const short* kp, float* Et)
{
    int wid  = threadIdx.x >> 6;
    int lane = threadIdx.x & 63;
    int g = blockIdx.x * 4 + wid;           // 0..2047
    int b = g >> 8, c = g & 255;
    int lrow = lane & 15;
    int q8   = (lane >> 4) << 3;
    const short* qb = qp + (size_t)(b * 256 + c) * 4096;
    const short* kb = kp + (size_t)(b * 256 + c) * 4096;

    f32x4 acc[4][4] = {};
#pragma unroll
    for (int ks = 0; ks < 2; ++ks) {
        int j0 = ks * 32 + q8;
        short8 A[4], Bv[4];
#pragma unroll
        for (int mi = 0; mi < 4; mi++)
            A[mi] = *(const short8*)(qb + (size_t)(mi * 16 + lrow) * 64 + j0);
#pragma unroll
        for (int ni = 0; ni < 4; ni++)
            Bv[ni] = *(const short8*)(kb + (size_t)(ni * 16 + lrow) * 64 + j0);
#pragma unroll
        for (int mi = 0; mi < 4; mi++)
#pragma unroll
            for (int ni = 0; ni < 4; ni++)
                acc[mi][ni] = mfma16(A[mi], Bv[ni], acc[mi][ni]);
    }
    int rq = (lane >> 4) * 4;
#pragma unroll
    for (int mi = 0; mi < 4; mi++)
#pragma unroll
        for (int r = 0; r < 4; r++) {
            int w = mi * 16 + rq + r;
            float* row = Et + ((size_t)(b * 256 + c) * 64 + w) * 64;
#pragma unroll
            for (int ni = 0; ni < 4; ni++)
                row[ni * 16 + lrow] = acc[mi][ni][r];
        }
}

// ---------- 4. softmax over c ----------
__global__ __launch_bounds__(256) void softmax_k(const float* Et, short* att)
{
    __shared__ float S[256 * 33];
    __shared__ float red[256];
    __shared__ float sm[256];
    int t  = threadIdx.x;
    int b  = blockIdx.x >> 7;
    int a  = (blockIdx.x >> 1) & 63;
    int jh = blockIdx.x & 1;

    const float* row = Et + ((size_t)(b * 256 + t) * 64 + a) * 64 + jh * 32;
#pragma unroll
    for (int jj = 0; jj < 32; jj += 4) {
        f32x4 v = *(const f32x4*)(row + jj);
#pragma unroll
        for (int l = 0; l < 4; l++) S[t * 33 + jj + l] = v[l];
    }
    __syncthreads();

    int tj = t & 31, tg = t >> 5;
    float m = -1e30f;
#pragma unroll
    for (int cc = 0; cc < 32; ++cc) m = fmaxf(m, S[(tg * 32 + cc) * 33 + tj]);
    red[t] = m;
    __syncthreads();
    if (tg == 0) {
        float mm = red[tj];
#pragma unroll
        for (int gg = 1; gg < 8; ++gg) mm = fmaxf(mm, red[gg * 32 + tj]);
        red[tj] = mm;
    }
    __syncthreads();
    float M = red[tj];
    float s = 0.f;
#pragma unroll
    for (int cc = 0; cc < 32; ++cc) {
        int id = (tg * 32 + cc) * 33 + tj;
        float e = __expf(S[id] - M);
        S[id] = e; s += e;
    }
    sm[t] = s;
    __syncthreads();
    if (tg == 0) {
        float ss = sm[tj];
#pragma unroll
        for (int gg = 1; gg < 8; ++gg) ss += sm[gg * 32 + tj];
        sm[tj] = 1.0f / ss;
    }
    __syncthreads();

    short* orow = att + ((size_t)(b * 256 + t) * 64 + a) * 64 + jh * 32;
#pragma unroll
    for (int jj = 0; jj < 32; jj += 8) {
        short8 o;
#pragma unroll
        for (int l = 0; l < 8; l++) o[l] = f2bf(S[t * 33 + jj + l] * sm[jj + l]);
        *(short8*)(orow + jj) = o;
    }
}

// ---------- 5. out: G[b,c,d,a] = sum_j vp[b,c,d,j] * Att[b,c,a,j] ----------
__global__ __launch_bounds__(256) void out_mfma(const short* vp, const short* att, short* G)
{
    int wid  = threadIdx.x >> 6;
    int lane = threadIdx.x & 63;
    int g = blockIdx.x * 4 + wid;
    int b = g >> 8, c = g & 255;
    int lrow = lane & 15;
    int q8   = (lane >> 4) << 3;
    const short* vb = vp  + (size_t)(b * 256 + c) * 4096;
    const short* ab = att + (size_t)(b * 256 + c) * 4096;

    f32x4 acc[4][4] = {};
#pragma unroll
    for (int ks = 0; ks < 2; ++ks) {
        int j0 = ks * 32 + q8;
        short8 A[4], Bv[4];
#pragma unroll
        for (int mi = 0; mi < 4; mi++)
            A[mi] = *(const short8*)(vb + (size_t)(mi * 16 + lrow) * 64 + j0);
#pragma unroll
        for (int ni = 0; ni < 4; ni++)
            Bv[ni] = *(const short8*)(ab + (size_t)(ni * 16 + lrow) * 64 + j0);
#pragma unroll
        for (int mi = 0; mi < 4; mi++)
#pragma unroll
            for (int ni = 0; ni < 4; ni++)
                acc[mi][ni] = mfma16(A[mi], Bv[ni], acc[mi][ni]);
    }
    int rq = (lane >> 4) * 4;
#pragma unroll
    for (int mi = 0; mi < 4; mi++)
#pragma unroll
        for (int r = 0; r < 4; r++) {
            int d = mi * 16 + rq + r;
            short* row = G + ((size_t)(b * 256 + c) * 64 + d) * 64;
#pragma unroll
            for (int ni = 0; ni < 4; ni++)
                row[ni * 16 + lrow] = f2bf(acc[mi][ni][r]);
        }
}

// ---------- 6. final: out[b,p,r,c] = gamma * G[b,c,r,p] + x[b,p,r,c] ----------
__global__ __launch_bounds__(256) void final_k(const short* G, const void* x,
                                               const void* gamma, void* out, const int* flagp)
{
    int f32 = *flagp;
    int t = threadIdx.x;               // = channel c
    int b = blockIdx.x >> 6, r = blockIdx.x & 63;
    const short* grow = G + ((size_t)(b * 256 + t) * 64 + r) * 64;
    float gm = f32 ? ((const float*)gamma)[0] : bf2f(((const short*)gamma)[0]);
    size_t obase = ((size_t)(b * 64) * 64 + r) * 256 + t;   // p stride 16384
    if (f32) {
        const float* xs = (const float*)x;
        float* os = (float*)out;
#pragma unroll
        for (int p8 = 0; p8 < 8; p8++) {
            short8 gv = *(const short8*)(grow + p8 * 8);
#pragma unroll
            for (int l = 0; l < 8; l++) {
                size_t off = obase + (size_t)(p8 * 8 + l) * 16384;
                os[off] = gm * bf2f(gv[l]) + xs[off];
            }
        }
    } else {
        const short* xs = (const short*)x;
        short* os = (short*)out;
#pragma unroll
        for (int p8 = 0; p8 < 8; p8++) {
            short8 gv = *(const short8*)(grow + p8 * 8);
#pragma unroll
            for (int l = 0; l < 8; l++) {
                size_t off = obase + (size_t)(p8 * 8 + l) * 16384;
                os[off] = f2bf(gm * bf2f(gv[l]) + bf2f(xs[off]));
            }
        }
    }
}

// ---------- launch ----------
extern "C" void kernel_launch(void* const* d_in, const int* in_sizes, int n_in,
                              void* d_out, int out_size, void* d_ws, size_t ws_size,
                              hipStream_t stream)
{
    const void* x   = d_in[0];
    Ptrs P{ d_in[1], d_in[3], d_in[5], d_in[7], d_in[9], d_in[11], d_in[13],
            d_in[2], d_in[4], d_in[6], d_in[8], d_in[10], d_in[12], d_in[14], d_in[15] };

    short* ws   = (short*)d_ws;
    short* qcat = ws;                     // R0: 8.4M bf16
    short* k1   = ws + 8388608;           // R1
    short* qp   = ws + 16777216;          // R2  q planar-T [b][c][w][h]
    short* kp   = ws + 25165824;          // R3  k planar   [b][c][h][w]
    short* vp   = ws + 33554432;          // R4  v planar   [b][c][h][w]
    short* wp   = ws + 41943040;          // packed weights
    short* bb   = ws + 43122688;          // biases + gamma
    int*   flag = (int*)(ws + 43123968);
    short* xb   = qp;                     // x bf16; dead before qp written
    float* Et   = (float*)d_ws;           // aliases R0+R1 (dead after dispatch B)
    short* att  = qp;                     // aliases R2 (qp dead after energy)
    short* G    = kp;                     // aliases R3 (kp dead after energy)

    detect_k<<<1, 256, 0, stream>>>((const short*)x, flag);
    convert_x<<<4096, 256, 0, stream>>>(x, xb, flag);
    convert_k<<<4612, 256, 0, stream>>>(P, wp, bb, flag);

    // dispatch A: all six x-reading convs fused (6144 waves)
    ConvJob ja{ xb, qcat, wp + 0,       bb + 0,   64,  1, 1, 0,   0 };
    ConvJob jb{ xb, vp,   wp + 1114112, bb + 768, 256, 1, 1, 0,   1 };
    ConvJob j1{ xb, qcat, wp + 16384,   bb + 64,  64,  1, 9, 64,  0 };
    ConvJob j2{ xb, qcat, wp + 163840,  bb + 128, 64,  3, 9, 128, 0 };
    ConvJob j3{ xb, qcat, wp + 311296,  bb + 192, 64,  6, 9, 192, 0 };
    ConvJob j4{ xb, k1,   wp + 524288,  bb + 512, 256, 1, 9, 0,   0 };
    ConvTable TA{ { ja, jb, j1, j2, j3, j4 }, { 512, 2560, 3072, 3584, 4096, 6144 } };
    conv_all<<<1536, 256, 0, stream>>>(TA);

    // dispatch B: q = 1x1(qcat) -> planar-T, k = 3x3(k1) -> planar (4096 waves)
    ConvJob j5{ qcat, qp, wp + 458752, bb + 256, 256, 1, 1, 0, 2 };
    ConvJob j6{ k1,   kp, wp + 524288, bb + 512, 256, 1, 9, 0, 1 };
    ConvTable TB{ { j5, j6, j6, j6, j6, j6 }, { 2048, 4096, 4096, 4096, 4096, 4096 } };
    conv_all<<<1024, 256, 0, stream>>>(TB);

    energy_mfma<<<512, 256, 0, stream>>>(qp, kp, Et);
    softmax_k<<<1024, 256, 0, stream>>>(Et, att);
    out_mfma<<<512, 256, 0, stream>>>(vp, att, G);
    final_k<<<512, 256, 0, stream>>>(G, x, d_in[15], d_out, flag);
}

// Round 7
// 414.660 us; speedup vs baseline: 1.6805x; 1.6805x over previous
//
#include <hip/hip_runtime.h>

// ---------- types ----------
typedef short  short8 __attribute__((ext_vector_type(8)));
typedef short  sv4    __attribute__((ext_vector_type(4)));   // 'short4' collides with HIP typedef
typedef __bf16 bf16x8 __attribute__((ext_vector_type(8)));
typedef float  f32x4  __attribute__((ext_vector_type(4)));

__device__ __forceinline__ float bf2f(short s) {
    unsigned u = ((unsigned)(unsigned short)s) << 16;
    return __builtin_bit_cast(float, u);
}
__device__ __forceinline__ short f2bf(float f) {
    unsigned u = __builtin_bit_cast(unsigned, f);
    u += 0x7fffu + ((u >> 16) & 1u);   // RNE
    return (short)(u >> 16);
}
__device__ __forceinline__ f32x4 mfma16(short8 a, short8 b, f32x4 c) {
    return __builtin_amdgcn_mfma_f32_16x16x32_bf16(
        __builtin_bit_cast(bf16x8, a), __builtin_bit_cast(bf16x8, b), c, 0, 0, 0);
}
// async global->LDS, 16B per lane; LDS dest = wave-uniform base + lane*16
__device__ __forceinline__ void gl16(const short* g, short* l) {
    __builtin_amdgcn_global_load_lds(
        (const __attribute__((address_space(1))) void*)g,
        (__attribute__((address_space(3))) void*)l, 16, 0, 0);
}

// Geometry: B=8, H=W=64, C=256, CQ=64
// x NHWC: idx = ((b*64+h)*64+w)*256 + c ; planar [b][c][h][w]

// ---------- 0. dtype detect ----------
__global__ __launch_bounds__(256) void detect_k(const short* x, int* flag)
{
    __shared__ int red[256];
    int t = threadIdx.x;
    int cnt = 0;
    for (int i = t; i < 4096; i += 256) {
        int e = (x[2 * i] >> 7) & 0xFF;
        cnt += (e >= 100 && e <= 140) ? 1 : 0;
    }
    red[t] = cnt; __syncthreads();
    for (int s = 128; s > 0; s >>= 1) { if (t < s) red[t] += red[t + s]; __syncthreads(); }
    if (t == 0) *flag = (red[0] < 3277) ? 1 : 0;   // 1 => inputs are fp32
}

// ---------- 1a. x -> bf16 ----------
__global__ __launch_bounds__(256) void convert_x(const void* x, short* xb, const int* flagp)
{
    int f32 = *flagp;
    size_t i = ((size_t)blockIdx.x * 256 + threadIdx.x) * 8;
    short8 v;
    if (f32) {
        const float* fs = (const float*)x + i;
        f32x4 a = *(const f32x4*)fs;
        f32x4 b = *(const f32x4*)(fs + 4);
#pragma unroll
        for (int l = 0; l < 4; l++) { v[l] = f2bf(a[l]); v[4 + l] = f2bf(b[l]); }
    } else {
        v = *(const short8*)((const short*)x + i);
    }
    *(short8*)(xb + i) = v;
}

// ---------- 1b. weight repack + bias concat + zero block ----------
struct Ptrs {
    const void *wq, *wq1, *wq2, *wq3, *wq4, *wk, *wv;
    const void *bq, *bq1, *bq2, *bq3, *bq4, *bk, *bv, *gm;
};

__global__ __launch_bounds__(256) void convert_k(Ptrs P, short* wp, short* bb, const int* flagp)
{
    int f32 = *flagp;
    int idx = blockIdx.x * 256 + threadIdx.x;
    if (idx < 1179648) {
        const void* src; int Cout, base;
        if      (idx <   16384) { src = P.wq;  Cout =  64; base = 0; }
        else if (idx <  163840) { src = P.wq1; Cout =  64; base = 16384; }
        else if (idx <  311296) { src = P.wq2; Cout =  64; base = 163840; }
        else if (idx <  458752) { src = P.wq3; Cout =  64; base = 311296; }
        else if (idx <  524288) { src = P.wq4; Cout = 256; base = 458752; }
        else if (idx < 1114112) { src = P.wk;  Cout = 256; base = 524288; }
        else                    { src = P.wv;  Cout = 256; base = 1114112; }
        int rem = idx - base;
        int t   = rem / (Cout * 256);
        int r2  = rem - t * Cout * 256;
        int co  = r2 >> 8;
        int ci  = r2 & 255;
        int si  = (t * 256 + ci) * Cout + co;
        wp[idx] = f32 ? f2bf(((const float*)src)[si]) : ((const short*)src)[si];
    } else if (idx < 1179648 + 1048) {
        int j = idx - 1179648;
        if (j < 1025) {
            const void* src; int off;
            if      (j <   64) { src = P.bq;  off = j; }
            else if (j <  128) { src = P.bq1; off = j - 64; }
            else if (j <  192) { src = P.bq2; off = j - 128; }
            else if (j <  256) { src = P.bq3; off = j - 192; }
            else if (j <  512) { src = P.bq4; off = j - 256; }
            else if (j <  768) { src = P.bk;  off = j - 512; }
            else if (j < 1024) { src = P.bv;  off = j - 768; }
            else               { src = P.gm;  off = 0; }
            bb[j] = f32 ? f2bf(((const float*)src)[off]) : ((const short*)src)[off];
        } else if (j >= 1032) {
            bb[j] = 0;                 // 16-short zero block for OOB staging
        }
    }
}

// ---------- 2. conv: m97-style block-tiled implicit GEMM ----------
// block = 4 waves. Cout=256: tile 128M x 128N (2x2 waves). Cout=64: 256M x 64N (4x1).
struct CJob {
    const short* src;   // NHWC bf16, Cin=256
    short*       dst;
    const short* wpk;   // packed [t][co][ci]
    const short* bias;
    int Cout;           // 64 or 256
    int dil;
    int ntaps;          // 1 or 9
    int coff;           // dst channel offset (outmode 0)
    int outmode;        // 0: NHWC64+coff  2: planar [b][c][h][w]  3: planar [b][c][w][h]
};
struct CTable { CJob j[6]; int end[6]; };

__global__ __launch_bounds__(256, 3) void conv_tile(CTable T, const short* zp)
{
    __shared__ short At[8192];   // up to 256 rows x 32 (16 KB)
    __shared__ short Bt[4096];   // up to 128 rows x 32 (8 KB)
    int tid = threadIdx.x;
    int ji = 0;
    while (ji < 5 && (int)blockIdx.x >= T.end[ji]) ji++;
    CJob J = T.j[ji];
    int g = blockIdx.x - (ji ? T.end[ji - 1] : 0);

    int big   = (J.Cout == 256);
    int BM    = big ? 128 : 256;
    int ntile = big ? (g & 1) : 0;
    int Mtile = big ? (g >> 1) : g;
    int p0 = Mtile * BM;
    int b  = p0 >> 12;
    int h0 = (p0 >> 6) & 63;

    int wave = tid >> 6, lane = tid & 63;
    int lrow = lane & 15, quad = lane >> 4;
    int m_base = big ? (wave & 1) * 64 : wave * 64;
    int n_base = big ? (wave >> 1) * 64 : 0;
    int sub8 = (lane & 3) * 8;

    // per-issue A row coords: issue ii = j*4+wave covers rows ii*16 + lane/4
    int hA[4], wA[4];
#pragma unroll
    for (int j = 0; j < 4; j++) {
        int m = (j * 4 + wave) * 16 + (lane >> 2);
        hA[j] = h0 + (m >> 6);
        wA[j] = m & 63;
    }
    int nA = big ? 2 : 4;      // A staging issues per wave (BM*64B / 1KB / 4 waves)

    f32x4 acc[4][4] = {};
    int steps = J.ntaps * 8;   // K-steps of 32
    for (int s = 0; s < steps; ++s) {
        int t = s >> 3, kc = s & 7;
        int dy = 0, dx = 0;
        if (J.ntaps == 9) {
            int tr = (t >= 6) ? 2 : ((t >= 3) ? 1 : 0);
            dy = (tr - 1) * J.dil;
            dx = (t - tr * 3 - 1) * J.dil;
        }
        int kco = kc * 32 + sub8;
        // ---- stage A tile (boundary lanes read the zero block) ----
#pragma unroll
        for (int j = 0; j < 4; j++) {
            if (j < nA) {
                int hh = hA[j] + dy, ww = wA[j] + dx;
                bool v = ((unsigned)hh < 64u) && ((unsigned)ww < 64u);
                const short* p = v ? (J.src + (((b * 64 + hh) * 64 + ww) * 256 + kco)) : zp;
                gl16(p, At + (j * 4 + wave) * 512);
            }
        }
        // ---- stage B tile ----
        const short* wpt = J.wpk + t * J.Cout * 256 + kco;
        if (big) {
#pragma unroll
            for (int j = 0; j < 2; j++) {
                int n = (j * 4 + wave) * 16 + (lane >> 2);
                gl16(wpt + (ntile * 128 + n) * 256, Bt + (j * 4 + wave) * 512);
            }
        } else {
            int n = wave * 16 + (lane >> 2);
            gl16(wpt + n * 256, Bt + wave * 512);
        }
        __syncthreads();          // compiler drains vmcnt before barrier
        short8 a4[4], b4[4];
#pragma unroll
        for (int mi = 0; mi < 4; mi++)
            a4[mi] = *(const short8*)(At + (m_base + mi * 16 + lrow) * 32 + quad * 8);
#pragma unroll
        for (int ni = 0; ni < 4; ni++)
            b4[ni] = *(const short8*)(Bt + (n_base + ni * 16 + lrow) * 32 + quad * 8);
#pragma unroll
        for (int mi = 0; mi < 4; mi++)
#pragma unroll
            for (int ni = 0; ni < 4; ni++)
                acc[mi][ni] = mfma16(a4[mi], b4[ni], acc[mi][ni]);
        __syncthreads();          // protect LDS reuse
    }

    int rq = quad * 4;
#pragma unroll
    for (int ni = 0; ni < 4; ni++) {
        int co = ntile * (big ? 128 : 64) + n_base + ni * 16 + lrow;
        float bv = bf2f(J.bias[co]);
        if (J.outmode == 0) {
#pragma unroll
            for (int mi = 0; mi < 4; mi++) {
                int pb = p0 + m_base + mi * 16 + rq;
#pragma unroll
                for (int r = 0; r < 4; r++)
                    J.dst[(size_t)(pb + r) * 256 + J.coff + co] = f2bf(acc[mi][ni][r] + bv);
            }
        } else if (J.outmode == 2) {   // planar [b][co][h][w]; big jobs only
            int h = h0 + (m_base >> 6);
            short* row = J.dst + ((size_t)(b * 256 + co) * 64 + h) * 64;
#pragma unroll
            for (int mi = 0; mi < 4; mi++) {
                sv4 o;
#pragma unroll
                for (int r = 0; r < 4; r++) o[r] = f2bf(acc[mi][ni][r] + bv);
                *(sv4*)(row + mi * 16 + rq) = o;
            }
        } else {                       // mode 3: planar-T [b][co][w][h]; big jobs only
            int h = h0 + (m_base >> 6);
            short* pl = J.dst + (size_t)(b * 256 + co) * 4096 + h;
#pragma unroll
            for (int mi = 0; mi < 4; mi++)
#pragma unroll
                for (int r = 0; r < 4; r++)
                    pl[(size_t)(mi * 16 + rq + r) * 64] = f2bf(acc[mi][ni][r] + bv);
        }
    }
}

// ---------- 3. energy: Et[b,c,w,i] = sum_j kp[b,c,i,j] * qp[b,c,w,j] ----------
__global__ __launch_bounds__(256) void energy_mfma(const short* qp, const short* kp, float* Et)
{
    int wid  = threadIdx.x >> 6;
    int lane = threadIdx.x & 63;
    int g = blockIdx.x * 4 + wid;           // 0..2047
    int b = g >> 8, c = g & 255;
    int lrow = lane & 15;
    int q8   = (lane >> 4) << 3;
    const short* qb = qp + (size_t)(b * 256 + c) * 4096;
    const short* kb = kp + (size_t)(b * 256 + c) * 4096;

    f32x4 acc[4][4] = {};
#pragma unroll
    for (int ks = 0; ks < 2; ++ks) {
        int j0 = ks * 32 + q8;
        short8 A[4], Bv[4];
#pragma unroll
        for (int mi = 0; mi < 4; mi++)
            A[mi] = *(const short8*)(qb + (size_t)(mi * 16 + lrow) * 64 + j0);
#pragma unroll
        for (int ni = 0; ni < 4; ni++)
            Bv[ni] = *(const short8*)(kb + (size_t)(ni * 16 + lrow) * 64 + j0);
#pragma unroll
        for (int mi = 0; mi < 4; mi++)
#pragma unroll
            for (int ni = 0; ni < 4; ni++)
                acc[mi][ni] = mfma16(A[mi], Bv[ni], acc[mi][ni]);
    }
    int rq = (lane >> 4) * 4;
#pragma unroll
    for (int mi = 0; mi < 4; mi++)
#pragma unroll
        for (int r = 0; r < 4; r++) {
            int w = mi * 16 + rq + r;
            float* row = Et + ((size_t)(b * 256 + c) * 64 + w) * 64;
#pragma unroll
            for (int ni = 0; ni < 4; ni++)
                row[ni * 16 + lrow] = acc[mi][ni][r];
        }
}

// ---------- 4. softmax over c ----------
__global__ __launch_bounds__(256) void softmax_k(const float* Et, short* att)
{
    __shared__ float S[256 * 33];
    __shared__ float red[256];
    __shared__ float sm[256];
    int t  = threadIdx.x;
    int b  = blockIdx.x >> 7;
    int a  = (blockIdx.x >> 1) & 63;
    int jh = blockIdx.x & 1;

    const float* row = Et + ((size_t)(b * 256 + t) * 64 + a) * 64 + jh * 32;
#pragma unroll
    for (int jj = 0; jj < 32; jj += 4) {
        f32x4 v = *(const f32x4*)(row + jj);
#pragma unroll
        for (int l = 0; l < 4; l++) S[t * 33 + jj + l] = v[l];
    }
    __syncthreads();

    int tj = t & 31, tg = t >> 5;
    float m = -1e30f;
#pragma unroll
    for (int cc = 0; cc < 32; ++cc) m = fmaxf(m, S[(tg * 32 + cc) * 33 + tj]);
    red[t] = m;
    __syncthreads();
    if (tg == 0) {
        float mm = red[tj];
#pragma unroll
        for (int gg = 1; gg < 8; ++gg) mm = fmaxf(mm, red[gg * 32 + tj]);
        red[tj] = mm;
    }
    __syncthreads();
    float M = red[tj];
    float s = 0.f;
#pragma unroll
    for (int cc = 0; cc < 32; ++cc) {
        int id = (tg * 32 + cc) * 33 + tj;
        float e = __expf(S[id] - M);
        S[id] = e; s += e;
    }
    sm[t] = s;
    __syncthreads();
    if (tg == 0) {
        float ss = sm[tj];
#pragma unroll
        for (int gg = 1; gg < 8; ++gg) ss += sm[gg * 32 + tj];
        sm[tj] = 1.0f / ss;
    }
    __syncthreads();

    short* orow = att + ((size_t)(b * 256 + t) * 64 + a) * 64 + jh * 32;
#pragma unroll
    for (int jj = 0; jj < 32; jj += 8) {
        short8 o;
#pragma unroll
        for (int l = 0; l < 8; l++) o[l] = f2bf(S[t * 33 + jj + l] * sm[jj + l]);
        *(short8*)(orow + jj) = o;
    }
}

// ---------- 5. out: G[b,c,d,a] = sum_j vp[b,c,d,j] * Att[b,c,a,j] ----------
__global__ __launch_bounds__(256) void out_mfma(const short* vp, const short* att, short* G)
{
    int wid  = threadIdx.x >> 6;
    int lane = threadIdx.x & 63;
    int g = blockIdx.x * 4 + wid;
    int b = g >> 8, c = g & 255;
    int lrow = lane & 15;
    int q8   = (lane >> 4) << 3;
    const short* vb = vp  + (size_t)(b * 256 + c) * 4096;
    const short* ab = att + (size_t)(b * 256 + c) * 4096;

    f32x4 acc[4][4] = {};
#pragma unroll
    for (int ks = 0; ks < 2; ++ks) {
        int j0 = ks * 32 + q8;
        short8 A[4], Bv[4];
#pragma unroll
        for (int mi = 0; mi < 4; mi++)
            A[mi] = *(const short8*)(vb + (size_t)(mi * 16 + lrow) * 64 + j0);
#pragma unroll
        for (int ni = 0; ni < 4; ni++)
            Bv[ni] = *(const short8*)(ab + (size_t)(ni * 16 + lrow) * 64 + j0);
#pragma unroll
        for (int mi = 0; mi < 4; mi++)
#pragma unroll
            for (int ni = 0; ni < 4; ni++)
                acc[mi][ni] = mfma16(A[mi], Bv[ni], acc[mi][ni]);
    }
    int rq = (lane >> 4) * 4;
#pragma unroll
    for (int mi = 0; mi < 4; mi++)
#pragma unroll
        for (int r = 0; r < 4; r++) {
            int d = mi * 16 + rq + r;
            short* row = G + ((size_t)(b * 256 + c) * 64 + d) * 64;
#pragma unroll
            for (int ni = 0; ni < 4; ni++)
                row[ni * 16 + lrow] = f2bf(acc[mi][ni][r]);
        }
}

// ---------- 6. final: out[b,p,r,c] = gamma * G[b,c,r,p] + x[b,p,r,c] ----------
__global__ __launch_bounds__(256) void final_k(const short* G, const void* x,
                                               const void* gamma, void* out, const int* flagp)
{
    int f32 = *flagp;
    int t = threadIdx.x;               // = channel c
    int b = blockIdx.x >> 6, r = blockIdx.x & 63;
    const short* grow = G + ((size_t)(b * 256 + t) * 64 + r) * 64;
    float gm = f32 ? ((const float*)gamma)[0] : bf2f(((const short*)gamma)[0]);
    size_t obase = ((size_t)(b * 64) * 64 + r) * 256 + t;   // p stride 16384
    if (f32) {
        const float* xs = (const float*)x;
        float* os = (float*)out;
#pragma unroll
        for (int p8 = 0; p8 < 8; p8++) {
            short8 gv = *(const short8*)(grow + p8 * 8);
#pragma unroll
            for (int l = 0; l < 8; l++) {
                size_t off = obase + (size_t)(p8 * 8 + l) * 16384;
                os[off] = gm * bf2f(gv[l]) + xs[off];
            }
        }
    } else {
        const short* xs = (const short*)x;
        short* os = (short*)out;
#pragma unroll
        for (int p8 = 0; p8 < 8; p8++) {
            short8 gv = *(const short8*)(grow + p8 * 8);
#pragma unroll
            for (int l = 0; l < 8; l++) {
                size_t off = obase + (size_t)(p8 * 8 + l) * 16384;
                os[off] = f2bf(gm * bf2f(gv[l]) + bf2f(xs[off]));
            }
        }
    }
}

// ---------- launch ----------
extern "C" void kernel_launch(void* const* d_in, const int* in_sizes, int n_in,
                              void* d_out, int out_size, void* d_ws, size_t ws_size,
                              hipStream_t stream)
{
    const void* x   = d_in[0];
    Ptrs P{ d_in[1], d_in[3], d_in[5], d_in[7], d_in[9], d_in[11], d_in[13],
            d_in[2], d_in[4], d_in[6], d_in[8], d_in[10], d_in[12], d_in[14], d_in[15] };

    short* ws   = (short*)d_ws;
    short* qcat = ws;                     // R0: 8.4M bf16
    short* k1   = ws + 8388608;           // R1
    short* qp   = ws + 16777216;          // R2  q planar-T [b][c][w][h]
    short* kp   = ws + 25165824;          // R3  k planar   [b][c][h][w]
    short* vp   = ws + 33554432;          // R4  v planar   [b][c][h][w]
    short* wp   = ws + 41943040;          // packed weights (1,179,648)
    short* bb   = ws + 43122688;          // biases(1025) + pad + zeros(16 @ +1032)
    int*   flag = (int*)(ws + 43123968);
    short* xb   = qp;                     // x bf16; dead before qp written
    float* Et   = (float*)d_ws;           // aliases R0+R1 (dead after dispatch B)
    short* att  = qp;                     // aliases R2 (qp dead after energy)
    short* G    = kp;                     // aliases R3 (kp dead after energy)
    const short* zp = bb + 1032;          // 16-B-aligned zero block

    detect_k<<<1, 256, 0, stream>>>((const short*)x, flag);
    convert_x<<<4096, 256, 0, stream>>>(x, xb, flag);
    convert_k<<<4613, 256, 0, stream>>>(P, wp, bb, flag);

    // dispatch A: all six x-reading convs (1536 blocks)
    CJob ja{ xb, qcat, wp + 0,       bb + 0,   64,  1, 1, 0,   0 };
    CJob jb{ xb, vp,   wp + 1114112, bb + 768, 256, 1, 1, 0,   2 };
    CJob j1{ xb, qcat, wp + 16384,   bb + 64,  64,  1, 9, 64,  0 };
    CJob j2{ xb, qcat, wp + 163840,  bb + 128, 64,  3, 9, 128, 0 };
    CJob j3{ xb, qcat, wp + 311296,  bb + 192, 64,  6, 9, 192, 0 };
    CJob j4{ xb, k1,   wp + 524288,  bb + 512, 256, 1, 9, 0,   0 };
    CTable TA{ { ja, jb, j1, j2, j3, j4 }, { 128, 640, 768, 896, 1024, 1536 } };
    conv_tile<<<1536, 256, 0, stream>>>(TA, zp);

    // dispatch B: q = 1x1(qcat) -> planar-T, k = 3x3(k1) -> planar (1024 blocks)
    CJob j5{ qcat, qp, wp + 458752, bb + 256, 256, 1, 1, 0, 3 };
    CJob j6{ k1,   kp, wp + 524288, bb + 512, 256, 1, 9, 0, 2 };
    CTable TB{ { j5, j6, j6, j6, j6, j6 }, { 512, 1024, 1024, 1024, 1024, 1024 } };
    conv_tile<<<1024, 256, 0, stream>>>(TB, zp);

    energy_mfma<<<512, 256, 0, stream>>>(qp, kp, Et);
    softmax_k<<<1024, 256, 0, stream>>>(Et, att);
    out_mfma<<<512, 256, 0, stream>>>(vp, att, G);
    final_k<<<512, 256, 0, stream>>>(G, x, d_in[15], d_out, flag);
}

// Round 8
// 405.836 us; speedup vs baseline: 1.7171x; 1.0217x over previous
//
#include <hip/hip_runtime.h>

// ---------- types ----------
typedef short  short8 __attribute__((ext_vector_type(8)));
typedef short  sv4    __attribute__((ext_vector_type(4)));   // 'short4' collides with HIP typedef
typedef __bf16 bf16x8 __attribute__((ext_vector_type(8)));
typedef float  f32x4  __attribute__((ext_vector_type(4)));

__device__ __forceinline__ float bf2f(short s) {
    unsigned u = ((unsigned)(unsigned short)s) << 16;
    return __builtin_bit_cast(float, u);
}
__device__ __forceinline__ short f2bf(float f) {
    unsigned u = __builtin_bit_cast(unsigned, f);
    u += 0x7fffu + ((u >> 16) & 1u);   // RNE
    return (short)(u >> 16);
}
__device__ __forceinline__ f32x4 mfma16(short8 a, short8 b, f32x4 c) {
    return __builtin_amdgcn_mfma_f32_16x16x32_bf16(
        __builtin_bit_cast(bf16x8, a), __builtin_bit_cast(bf16x8, b), c, 0, 0, 0);
}
// async global->LDS, 16B/lane; LDS dest = wave-uniform base + lane*16
__device__ __forceinline__ void gl16(const short* g, short* l) {
    __builtin_amdgcn_global_load_lds(
        (const __attribute__((address_space(1))) void*)g,
        (__attribute__((address_space(3))) void*)l, 16, 0, 0);
}

// Geometry: B=8, H=W=64, C=256, CQ=64
// x NHWC: idx = ((b*64+h)*64+w)*256 + c ; planar [b][c][h][w]

// ---------- 0. dtype detect ----------
__global__ __launch_bounds__(256) void detect_k(const short* x, int* flag)
{
    __shared__ int red[256];
    int t = threadIdx.x;
    int cnt = 0;
    for (int i = t; i < 4096; i += 256) {
        int e = (x[2 * i] >> 7) & 0xFF;
        cnt += (e >= 100 && e <= 140) ? 1 : 0;
    }
    red[t] = cnt; __syncthreads();
    for (int s = 128; s > 0; s >>= 1) { if (t < s) red[t] += red[t + s]; __syncthreads(); }
    if (t == 0) *flag = (red[0] < 3277) ? 1 : 0;   // 1 => inputs are fp32
}

// ---------- 1a. x -> bf16 ----------
__global__ __launch_bounds__(256) void convert_x(const void* x, short* xb, const int* flagp)
{
    int f32 = *flagp;
    size_t i = ((size_t)blockIdx.x * 256 + threadIdx.x) * 8;
    short8 v;
    if (f32) {
        const float* fs = (const float*)x + i;
        f32x4 a = *(const f32x4*)fs;
        f32x4 b = *(const f32x4*)(fs + 4);
#pragma unroll
        for (int l = 0; l < 4; l++) { v[l] = f2bf(a[l]); v[4 + l] = f2bf(b[l]); }
    } else {
        v = *(const short8*)((const short*)x + i);
    }
    *(short8*)(xb + i) = v;
}

// ---------- 1b. weight repack + bias concat + zero block ----------
struct Ptrs {
    const void *wq, *wq1, *wq2, *wq3, *wq4, *wk, *wv;
    const void *bq, *bq1, *bq2, *bq3, *bq4, *bk, *bv, *gm;
};

__global__ __launch_bounds__(256) void convert_k(Ptrs P, short* wp, short* bb, const int* flagp)
{
    int f32 = *flagp;
    int idx = blockIdx.x * 256 + threadIdx.x;
    if (idx < 1179648) {
        const void* src; int Cout, base;
        if      (idx <   16384) { src = P.wq;  Cout =  64; base = 0; }
        else if (idx <  163840) { src = P.wq1; Cout =  64; base = 16384; }
        else if (idx <  311296) { src = P.wq2; Cout =  64; base = 163840; }
        else if (idx <  458752) { src = P.wq3; Cout =  64; base = 311296; }
        else if (idx <  524288) { src = P.wq4; Cout = 256; base = 458752; }
        else if (idx < 1114112) { src = P.wk;  Cout = 256; base = 524288; }
        else                    { src = P.wv;  Cout = 256; base = 1114112; }
        int rem = idx - base;
        int t   = rem / (Cout * 256);
        int r2  = rem - t * Cout * 256;
        int co  = r2 >> 8;
        int ci  = r2 & 255;
        int si  = (t * 256 + ci) * Cout + co;
        wp[idx] = f32 ? f2bf(((const float*)src)[si]) : ((const short*)src)[si];
    } else if (idx < 1179648 + 1048) {
        int j = idx - 1179648;
        if (j < 1025) {
            const void* src; int off;
            if      (j <   64) { src = P.bq;  off = j; }
            else if (j <  128) { src = P.bq1; off = j - 64; }
            else if (j <  192) { src = P.bq2; off = j - 128; }
            else if (j <  256) { src = P.bq3; off = j - 192; }
            else if (j <  512) { src = P.bq4; off = j - 256; }
            else if (j <  768) { src = P.bk;  off = j - 512; }
            else if (j < 1024) { src = P.bv;  off = j - 768; }
            else               { src = P.gm;  off = 0; }
            bb[j] = f32 ? f2bf(((const float*)src)[off]) : ((const short*)src)[off];
        } else if (j >= 1032) {
            bb[j] = 0;                 // 16-short zero block for OOB staging
        }
    }
}

// ---------- 2. conv: block-tiled implicit GEMM, BK=64, XOR-swizzled LDS ----------
// block = 4 waves. Cout=256: 128M x 128N (2x2 waves). Cout=64: 256M x 64N (4x1).
// LDS row = 64 shorts (128B); logical chunk c (8 shorts) of row r stored at chunk c^(r&7).
struct CJob {
    const short* src;   // NHWC bf16, Cin=256
    short*       dst;
    const short* wpk;   // packed [t][co][ci]
    const short* bias;
    int Cout;           // 64 or 256
    int dil;
    int ntaps;          // 1 or 9
    int coff;           // dst channel offset (outmode 0)
    int outmode;        // 0: NHWC+coff  2: planar [b][c][h][w]  3: planar [b][c][w][h]
};
struct CTable { CJob j[6]; int end[6]; };

__global__ __launch_bounds__(256, 4) void conv_tile(CTable T, const short* zp)
{
    __shared__ short Sh[20480];   // 40 KB: A at 0, B at bofs
    int tid = threadIdx.x;
    int ji = 0;
    while (ji < 5 && (int)blockIdx.x >= T.end[ji]) ji++;
    CJob J = T.j[ji];
    int g = blockIdx.x - (ji ? T.end[ji - 1] : 0);

    int big   = (J.Cout == 256);
    int BM    = big ? 128 : 256;
    int ntile = big ? (g & 1) : 0;
    int Mtile = big ? (g >> 1) : g;
    int p0 = Mtile * BM;
    int b  = p0 >> 12;
    int h0 = (p0 >> 6) & 63;
    int bofs = big ? 8192 : 16384;
    int nt0  = ntile * 128;

    int wave = tid >> 6, lane = tid & 63;
    int lrow = lane & 15, quad = lane >> 4;
    int m_base = big ? (wave & 1) * 64 : wave * 64;
    int n_base = big ? (wave >> 1) * 64 : 0;

    int lr8 = lane >> 3;                        // row within 8-row issue
    int cl  = (lane & 7) ^ (lr8 & 7);           // logical chunk this lane stages
    int nAiss = big ? 4 : 8;                    // A issues per wave
    int nBiss = big ? 4 : 2;                    // B issues per wave

    // fragment physical-chunk offsets (shorts) for k-slice j
    int pc0 = ((quad     ^ (lrow & 7)) * 8);
    int pc1 = (((4 + quad) ^ (lrow & 7)) * 8);

    f32x4 acc[4][4] = {};
    int steps = J.ntaps * 4;                    // K-steps of 64
    for (int s = 0; s < steps; ++s) {
        int t = s >> 2, s4 = s & 3;
        int dy = 0, dx = 0;
        if (J.ntaps == 9) {
            int tr = (t >= 6) ? 2 : ((t >= 3) ? 1 : 0);
            dy = (tr - 1) * J.dil;
            dx = (t - tr * 3 - 1) * J.dil;
        }
        int kco = s4 * 64 + cl * 8;
        // ---- stage A (rows = positions); invalid lanes read zero block ----
        for (int jj = 0; jj < nAiss; jj++) {
            int m  = (jj * 4 + wave) * 8 + lr8;
            int hh = h0 + (m >> 6) + dy;
            int ww = (m & 63) + dx;
            bool v = ((unsigned)hh < 64u) && ((unsigned)ww < 64u);
            const short* p = v ? (J.src + (((b * 64 + hh) * 64 + ww) * 256 + kco)) : zp;
            gl16(p, Sh + (jj * 4 + wave) * 512);
        }
        // ---- stage B (rows = output channels) ----
        const short* wpt = J.wpk + t * J.Cout * 256 + kco;
        for (int jj = 0; jj < nBiss; jj++) {
            int n = (jj * 4 + wave) * 8 + lr8;
            gl16(wpt + (size_t)(nt0 + n) * 256, Sh + bofs + (jj * 4 + wave) * 512);
        }
        __syncthreads();
        // ---- compute: 2 k-slices of 32 ----
#pragma unroll
        for (int j = 0; j < 2; j++) {
            int pc = j ? pc1 : pc0;
            short8 a4[4], b4[4];
#pragma unroll
            for (int mi = 0; mi < 4; mi++)
                a4[mi] = *(const short8*)(Sh + (m_base + mi * 16 + lrow) * 64 + pc);
#pragma unroll
            for (int ni = 0; ni < 4; ni++)
                b4[ni] = *(const short8*)(Sh + bofs + (n_base + ni * 16 + lrow) * 64 + pc);
#pragma unroll
            for (int mi = 0; mi < 4; mi++)
#pragma unroll
                for (int ni = 0; ni < 4; ni++)
                    acc[mi][ni] = mfma16(a4[mi], b4[ni], acc[mi][ni]);
        }
        __syncthreads();
    }

    int rq = quad * 4;
#pragma unroll
    for (int ni = 0; ni < 4; ni++) {
        int co = nt0 + n_base + ni * 16 + lrow;
        float bv = bf2f(J.bias[co]);
        if (J.outmode == 0) {
#pragma unroll
            for (int mi = 0; mi < 4; mi++) {
                int pb = p0 + m_base + mi * 16 + rq;
#pragma unroll
                for (int r = 0; r < 4; r++)
                    J.dst[(size_t)(pb + r) * 256 + J.coff + co] = f2bf(acc[mi][ni][r] + bv);
            }
        } else if (J.outmode == 2) {   // planar [b][co][h][w]; big jobs only
            int h = h0 + (m_base >> 6);
            short* row = J.dst + ((size_t)(b * 256 + co) * 64 + h) * 64;
#pragma unroll
            for (int mi = 0; mi < 4; mi++) {
                sv4 o;
#pragma unroll
                for (int r = 0; r < 4; r++) o[r] = f2bf(acc[mi][ni][r] + bv);
                *(sv4*)(row + mi * 16 + rq) = o;
            }
        } else {                       // mode 3: planar-T [b][co][w][h]; big jobs only
            int h = h0 + (m_base >> 6);
            short* pl = J.dst + (size_t)(b * 256 + co) * 4096 + h;
#pragma unroll
            for (int mi = 0; mi < 4; mi++)
#pragma unroll
                for (int r = 0; r < 4; r++)
                    pl[(size_t)(mi * 16 + rq + r) * 64] = f2bf(acc[mi][ni][r] + bv);
        }
    }
}

// ---------- 3. energy: Et[b,c,w,i] = sum_j kp[b,c,i,j] * qp[b,c,w,j] ----------
__global__ __launch_bounds__(256) void energy_mfma(const short* qp, const short* kp, float* Et)
{
    int wid  = threadIdx.x >> 6;
    int lane = threadIdx.x & 63;
    int g = blockIdx.x * 4 + wid;           // 0..2047
    int b = g >> 8, c = g & 255;
    int lrow = lane & 15;
    int q8   = (lane >> 4) << 3;
    const short* qb = qp + (size_t)(b * 256 + c) * 4096;
    const short* kb = kp + (size_t)(b * 256 + c) * 4096;

    f32x4 acc[4][4] = {};
#pragma unroll
    for (int ks = 0; ks < 2; ++ks) {
        int j0 = ks * 32 + q8;
        short8 A[4], Bv[4];
#pragma unroll
        for (int mi = 0; mi < 4; mi++)
            A[mi] = *(const short8*)(qb + (size_t)(mi * 16 + lrow) * 64 + j0);
#pragma unroll
        for (int ni = 0; ni < 4; ni++)
            Bv[ni] = *(const short8*)(kb + (size_t)(ni * 16 + lrow) * 64 + j0);
#pragma unroll
        for (int mi = 0; mi < 4; mi++)
#pragma unroll
            for (int ni = 0; ni < 4; ni++)
                acc[mi][ni] = mfma16(A[mi], Bv[ni], acc[mi][ni]);
    }
    int rq = (lane >> 4) * 4;
#pragma unroll
    for (int mi = 0; mi < 4; mi++)
#pragma unroll
        for (int r = 0; r < 4; r++) {
            int w = mi * 16 + rq + r;
            float* row = Et + ((size_t)(b * 256 + c) * 64 + w) * 64;
#pragma unroll
            for (int ni = 0; ni < 4; ni++)
                row[ni * 16 + lrow] = acc[mi][ni][r];
        }
}

// ---------- 4. softmax over c ----------
__global__ __launch_bounds__(256) void softmax_k(const float* Et, short* att)
{
    __shared__ float S[256 * 33];
    __shared__ float red[256];
    __shared__ float sm[256];
    int t  = threadIdx.x;
    int b  = blockIdx.x >> 7;
    int a  = (blockIdx.x >> 1) & 63;
    int jh = blockIdx.x & 1;

    const float* row = Et + ((size_t)(b * 256 + t) * 64 + a) * 64 + jh * 32;
#pragma unroll
    for (int jj = 0; jj < 32; jj += 4) {
        f32x4 v = *(const f32x4*)(row + jj);
#pragma unroll
        for (int l = 0; l < 4; l++) S[t * 33 + jj + l] = v[l];
    }
    __syncthreads();

    int tj = t & 31, tg = t >> 5;
    float m = -1e30f;
#pragma unroll
    for (int cc = 0; cc < 32; ++cc) m = fmaxf(m, S[(tg * 32 + cc) * 33 + tj]);
    red[t] = m;
    __syncthreads();
    if (tg == 0) {
        float mm = red[tj];
#pragma unroll
        for (int gg = 1; gg < 8; ++gg) mm = fmaxf(mm, red[gg * 32 + tj]);
        red[tj] = mm;
    }
    __syncthreads();
    float M = red[tj];
    float s = 0.f;
#pragma unroll
    for (int cc = 0; cc < 32; ++cc) {
        int id = (tg * 32 + cc) * 33 + tj;
        float e = __expf(S[id] - M);
        S[id] = e; s += e;
    }
    sm[t] = s;
    __syncthreads();
    if (tg == 0) {
        float ss = sm[tj];
#pragma unroll
        for (int gg = 1; gg < 8; ++gg) ss += sm[gg * 32 + tj];
        sm[tj] = 1.0f / ss;
    }
    __syncthreads();

    short* orow = att + ((size_t)(b * 256 + t) * 64 + a) * 64 + jh * 32;
#pragma unroll
    for (int jj = 0; jj < 32; jj += 8) {
        short8 o;
#pragma unroll
        for (int l = 0; l < 8; l++) o[l] = f2bf(S[t * 33 + jj + l] * sm[jj + l]);
        *(short8*)(orow + jj) = o;
    }
}

// ---------- 5. out: G[b,c,d,a] = sum_j vp[b,c,d,j] * Att[b,c,a,j] ----------
__global__ __launch_bounds__(256) void out_mfma(const short* vp, const short* att, short* G)
{
    int wid  = threadIdx.x >> 6;
    int lane = threadIdx.x & 63;
    int g = blockIdx.x * 4 + wid;
    int b = g >> 8, c = g & 255;
    int lrow = lane & 15;
    int q8   = (lane >> 4) << 3;
    const short* vb = vp  + (size_t)(b * 256 + c) * 4096;
    const short* ab = att + (size_t)(b * 256 + c) * 4096;

    f32x4 acc[4][4] = {};
#pragma unroll
    for (int ks = 0; ks < 2; ++ks) {
        int j0 = ks * 32 + q8;
        short8 A[4], Bv[4];
#pragma unroll
        for (int mi = 0; mi < 4; mi++)
            A[mi] = *(const short8*)(vb + (size_t)(mi * 16 + lrow) * 64 + j0);
#pragma unroll
        for (int ni = 0; ni < 4; ni++)
            Bv[ni] = *(const short8*)(ab + (size_t)(ni * 16 + lrow) * 64 + j0);
#pragma unroll
        for (int mi = 0; mi < 4; mi++)
#pragma unroll
            for (int ni = 0; ni < 4; ni++)
                acc[mi][ni] = mfma16(A[mi], Bv[ni], acc[mi][ni]);
    }
    int rq = (lane >> 4) * 4;
#pragma unroll
    for (int mi = 0; mi < 4; mi++)
#pragma unroll
        for (int r = 0; r < 4; r++) {
            int d = mi * 16 + rq + r;
            short* row = G + ((size_t)(b * 256 + c) * 64 + d) * 64;
#pragma unroll
            for (int ni = 0; ni < 4; ni++)
                row[ni * 16 + lrow] = f2bf(acc[mi][ni][r]);
        }
}

// ---------- 6. final: out[b,p,r,c] = gamma * G[b,c,r,p] + x[b,p,r,c] ----------
__global__ __launch_bounds__(256) void final_k(const short* G, const void* x,
                                               const void* gamma, void* out, const int* flagp)
{
    int f32 = *flagp;
    int t = threadIdx.x;               // = channel c
    int b = blockIdx.x >> 6, r = blockIdx.x & 63;
    const short* grow = G + ((size_t)(b * 256 + t) * 64 + r) * 64;
    float gm = f32 ? ((const float*)gamma)[0] : bf2f(((const short*)gamma)[0]);
    size_t obase = ((size_t)(b * 64) * 64 + r) * 256 + t;   // p stride 16384
    if (f32) {
        const float* xs = (const float*)x;
        float* os = (float*)out;
#pragma unroll
        for (int p8 = 0; p8 < 8; p8++) {
            short8 gv = *(const short8*)(grow + p8 * 8);
#pragma unroll
            for (int l = 0; l < 8; l++) {
                size_t off = obase + (size_t)(p8 * 8 + l) * 16384;
                os[off] = gm * bf2f(gv[l]) + xs[off];
            }
        }
    } else {
        const short* xs = (const short*)x;
        short* os = (short*)out;
#pragma unroll
        for (int p8 = 0; p8 < 8; p8++) {
            short8 gv = *(const short8*)(grow + p8 * 8);
#pragma unroll
            for (int l = 0; l < 8; l++) {
                size_t off = obase + (size_t)(p8 * 8 + l) * 16384;
                os[off] = f2bf(gm * bf2f(gv[l]) + bf2f(xs[off]));
            }
        }
    }
}

// ---------- launch ----------
extern "C" void kernel_launch(void* const* d_in, const int* in_sizes, int n_in,
                              void* d_out, int out_size, void* d_ws, size_t ws_size,
                              hipStream_t stream)
{
    const void* x   = d_in[0];
    Ptrs P{ d_in[1], d_in[3], d_in[5], d_in[7], d_in[9], d_in[11], d_in[13],
            d_in[2], d_in[4], d_in[6], d_in[8], d_in[10], d_in[12], d_in[14], d_in[15] };

    short* ws   = (short*)d_ws;
    short* qcat = ws;                     // R0: 8.4M bf16
    short* k1   = ws + 8388608;           // R1
    short* qp   = ws + 16777216;          // R2  q planar-T [b][c][w][h]
    short* kp   = ws + 25165824;          // R3  k planar   [b][c][h][w]
    short* vp   = ws + 33554432;          // R4  v planar   [b][c][h][w]
    short* wp   = ws + 41943040;          // packed weights (1,179,648)
    short* bb   = ws + 43122688;          // biases(1025) + pad + zeros(16 @ +1032)
    int*   flag = (int*)(ws + 43123968);
    short* xb   = qp;                     // x bf16; dead before qp written
    float* Et   = (float*)d_ws;           // aliases R0+R1 (dead after dispatch B)
    short* att  = qp;                     // aliases R2 (qp dead after energy)
    short* G    = kp;                     // aliases R3 (kp dead after energy)
    const short* zp = bb + 1032;          // 16-B-aligned zero block

    detect_k<<<1, 256, 0, stream>>>((const short*)x, flag);
    convert_x<<<4096, 256, 0, stream>>>(x, xb, flag);
    convert_k<<<4613, 256, 0, stream>>>(P, wp, bb, flag);

    // dispatch A: six x-reading convs, LONG jobs first (1536 blocks)
    CJob j4{ xb, k1,   wp + 524288,  bb + 512, 256, 1, 9, 0,   0 };
    CJob j1{ xb, qcat, wp + 16384,   bb + 64,  64,  1, 9, 64,  0 };
    CJob j2{ xb, qcat, wp + 163840,  bb + 128, 64,  3, 9, 128, 0 };
    CJob j3{ xb, qcat, wp + 311296,  bb + 192, 64,  6, 9, 192, 0 };
    CJob jb{ xb, vp,   wp + 1114112, bb + 768, 256, 1, 1, 0,   2 };
    CJob ja{ xb, qcat, wp + 0,       bb + 0,   64,  1, 1, 0,   0 };
    CTable TA{ { j4, j1, j2, j3, jb, ja }, { 512, 640, 768, 896, 1408, 1536 } };
    conv_tile<<<1536, 256, 0, stream>>>(TA, zp);

    // dispatch B: k = 3x3(k1) -> planar first, then q = 1x1(qcat) -> planar-T
    CJob j6{ k1,   kp, wp + 524288, bb + 512, 256, 1, 9, 0, 2 };
    CJob j5{ qcat, qp, wp + 458752, bb + 256, 256, 1, 1, 0, 3 };
    CTable TB{ { j6, j5, j5, j5, j5, j5 }, { 512, 1024, 1024, 1024, 1024, 1024 } };
    conv_tile<<<1024, 256, 0, stream>>>(TB, zp);

    energy_mfma<<<512, 256, 0, stream>>>(qp, kp, Et);
    softmax_k<<<1024, 256, 0, stream>>>(Et, att);
    out_mfma<<<512, 256, 0, stream>>>(vp, att, G);
    final_k<<<512, 256, 0, stream>>>(G, x, d_in[15], d_out, flag);
}